// Round 5
// baseline (2027.148 us; speedup 1.0000x reference)
//
#include <hip/hip_runtime.h>
#include <hip/hip_fp16.h>

// Problem constants (from reference)
#define NB   2048   // batch
#define S    256    // scratchpad slots
#define D    64     // feature dim
#define H    4      // heads
#define HID  128    // MLP hidden
#define TPB  256

__device__ __forceinline__ float wred_sum(float v){
#pragma unroll
  for (int m = 32; m >= 1; m >>= 1) v += __shfl_xor(v, m, 64);
  return v;
}

__device__ __forceinline__ unsigned h2u(__half2 h){ union{__half2 h; unsigned u;} c; c.h=h; return c.u; }
__device__ __forceinline__ __half2 u2h(unsigned u){ union{__half2 h; unsigned u;} c; c.u=u; return c.h; }

// y[j] = bias[j] + sum_{i<64} x[i]*W[i*64+j]  -- split-K across lane quadrants,
// wave w owns outputs [16w,16w+16); intra-wave shfl reduce; no cross-wave sync.
__device__ __forceinline__ void matvec64(const float* __restrict__ W,
                                         const float* __restrict__ bias,
                                         const float* x, float* y,
                                         int wid, int lane) {
  const int j  = wid * 16 + (lane & 15);
  const int i0 = (lane >> 4) * 16;
  float acc = 0.f;
#pragma unroll
  for (int i = 0; i < 16; ++i) acc += x[i0 + i] * W[(i0 + i) * 64 + j];
  acc += __shfl_xor(acc, 16, 64);
  acc += __shfl_xor(acc, 32, 64);
  if (lane < 16) y[j] = acc + bias[j];
}

__global__ __launch_bounds__(TPB, 4)
void engine_kernel(const float* __restrict__ sp_init,
                   const float* __restrict__ ptr_init,
                   const float* __restrict__ wq, const float* __restrict__ bq,
                   const float* __restrict__ wk, const float* __restrict__ bk,
                   const float* __restrict__ wv, const float* __restrict__ bv,
                   const float* __restrict__ wo, const float* __restrict__ bo,
                   const float* __restrict__ ww, const float* __restrict__ bw,
                   const float* __restrict__ aw1, const float* __restrict__ ab1,
                   const float* __restrict__ aw2, const float* __restrict__ ab2,
                   const int*   __restrict__ nsteps,
                   float* __restrict__ out)
{
  // fp16 mirror of sp, row-padded to 66 halves (132B): column access (uniform s
  // per instr, lanes over d) is a row read -> conflict-free. Master sp state
  // stays fp32 in registers (thread owns row tid).
  __shared__ __half  spm[S][66];                 // 33792 B (reused as fp32 stage at end)
  __shared__ float4  qkT[D];                     //  1024 B (qk packed by head)
  __shared__ float4  red4[4];                    //    64 B (P5 softmax partials)
  __shared__ __align__(16) float hidden[HID];    //   512 B
  __shared__ float   ctxv[H][D];                 //  1024 B (atomic target)
  __shared__ float   regv[D];                    //   256 B (atomic target)
  __shared__ float   qhv[D], readf[D], readv[D], wvalv[D]; // 1024 B
  __shared__ unsigned attnLo[S], attnHi[S];      //  2048 B (attn fp16x4)
  __shared__ __half  addrh[S];                   //   512 B (addr_r fp16)
  __shared__ float   red_p1[4], red9[4];         //    32 B
  __shared__ float   qbv[H];                     //    16 B
  // total ~40304 B <= 40960 -> 4 blocks/CU (VGPR<=128 via launch_bounds)

  const int tid  = threadIdx.x;
  const int wid  = tid >> 6;
  const int lane = tid & 63;

  // ---- staging: row tid of sp into registers + fp16 mirror
  float sp_reg[D];
  {
    const float4* src = reinterpret_cast<const float4*>(sp_init + tid * D);
#pragma unroll
    for (int k = 0; k < 16; ++k) {
      float4 v = src[k];
      sp_reg[4*k+0] = v.x; sp_reg[4*k+1] = v.y; sp_reg[4*k+2] = v.z; sp_reg[4*k+3] = v.w;
    }
    __half2* rowp = reinterpret_cast<__half2*>(&spm[tid][0]);
#pragma unroll
    for (int p = 0; p < 32; ++p)
      rowp[p] = __float22half2_rn(make_float2(sp_reg[2*p], sp_reg[2*p+1]));
    if (tid < 64) regv[tid] = 0.f;
    ((float*)ctxv)[tid] = 0.f;
  }
  float p0 = ptr_init[0];
  const int T = *nsteps;
  const float posq = (float)tid * (1.0f / 255.0f);  // linspace(0,1,256)[tid]
  __syncthreads();

  for (int t = 0; t < T; ++t) {
    // ---- P1: addr_r = softmax(-10|pos-p0|). exp in [e^-10,1] -> no max needed.
    {
      float a = __expf(-10.0f * fabsf(posq - p0));
      float ss = wred_sum(a);
      if (lane == 0) red_p1[wid] = ss;
      __syncthreads();                                        // B1
      ss = red_p1[0] + red_p1[1] + red_p1[2] + red_p1[3];
      addrh[tid] = __float2half(a / ss);
    }
    __syncthreads();                                          // B2

    // ---- P2: regv[d] += sum_{s in wave chunk} addr_r[s]*sp16[s][d]
    {
      const int d = lane, s0 = wid * 64;
      float acc = 0.f;
#pragma unroll 16
      for (int i = 0; i < 64; ++i) {
        int s = s0 + i;
        acc += __half2float(addrh[s]) * __half2float(spm[s][d]);
      }
      atomicAdd(&regv[d], acc);
    }
    __syncthreads();                                          // B3

    // ---- P3: qh = regv @ wq + bq
    matvec64(wq, bq, regv, qhv, wid, lane);
    __syncthreads();                                          // B4

    // ---- P4: qk[h][e] = sum_j wk[e][16h+j]*qh[16h+j]; qb[h] = qh_h . bk_h
    {
      const int h = wid, e = lane;
      float acc = 0.f;
#pragma unroll
      for (int j = 0; j < 16; ++j) acc += wk[e * 64 + h * 16 + j] * qhv[h * 16 + j];
      ((float*)qkT)[e * 4 + h] = acc;
      if (tid < 4) {
        float qb = 0.f;
#pragma unroll
        for (int j = 0; j < 16; ++j) qb += qhv[tid * 16 + j] * bk[tid * 16 + j];
        qbv[tid] = qb;
      }
      if (tid < 64) regv[tid] = 0.f;   // re-arm P2 accumulator (dead until next step)
    }
    __syncthreads();                                          // B5

    // ---- P5: scores from REGISTER sp + qkT broadcast; per-head softmax (no max:
    //          logits bounded to a few units -> fp32 exp safe)
    {
      float s0 = qbv[0], s1 = qbv[1], s2 = qbv[2], s3 = qbv[3];
#pragma unroll
      for (int e = 0; e < 64; ++e) {
        float4 qk = qkT[e];                 // LDS b128 broadcast
        float v = sp_reg[e];
        s0 += v * qk.x; s1 += v * qk.y; s2 += v * qk.z; s3 += v * qk.w;
      }
      float e0 = __expf(s0 * 0.25f), e1 = __expf(s1 * 0.25f);
      float e2 = __expf(s2 * 0.25f), e3 = __expf(s3 * 0.25f);
      float r0 = e0, r1 = e1, r2 = e2, r3 = e3;
#pragma unroll
      for (int m = 32; m >= 1; m >>= 1) {
        r0 += __shfl_xor(r0, m, 64); r1 += __shfl_xor(r1, m, 64);
        r2 += __shfl_xor(r2, m, 64); r3 += __shfl_xor(r3, m, 64);
      }
      if (lane == 0) red4[wid] = make_float4(r0, r1, r2, r3);
      __syncthreads();                                        // B6
      float4 t0 = red4[0], t1 = red4[1], t2 = red4[2], t3 = red4[3];
      float i0 = 1.0f / (t0.x + t1.x + t2.x + t3.x);
      float i1 = 1.0f / (t0.y + t1.y + t2.y + t3.y);
      float i2 = 1.0f / (t0.z + t1.z + t2.z + t3.z);
      float i3 = 1.0f / (t0.w + t1.w + t2.w + t3.w);
      attnLo[tid] = h2u(__float22half2_rn(make_float2(e0 * i0, e1 * i1)));
      attnHi[tid] = h2u(__float22half2_rn(make_float2(e2 * i2, e3 * i3)));
      ((float*)ctxv)[tid] = 0.f;          // re-arm P6 accumulator (dead since P7a(t-1))
    }
    __syncthreads();                                          // B7

    // ---- P6: ctx[h][d] += sum_{s in chunk} attn[h][s]*sp16[s][d]
    {
      const int d = lane, s0 = wid * 64;
      float c0 = 0, c1 = 0, c2 = 0, c3 = 0;
#pragma unroll 8
      for (int i = 0; i < 64; ++i) {
        int s = s0 + i;
        float sv = __half2float(spm[s][d]);
        float2 fl = __half22float2(u2h(attnLo[s]));
        float2 fh = __half22float2(u2h(attnHi[s]));
        c0 += fl.x * sv; c1 += fl.y * sv; c2 += fh.x * sv; c3 += fh.y * sv;
      }
      atomicAdd(&ctxv[0][d], c0); atomicAdd(&ctxv[1][d], c1);
      atomicAdd(&ctxv[2][d], c2); atomicAdd(&ctxv[3][d], c3);
    }
    __syncthreads();                                          // B8

    // ---- P7a: readf[f] = ctx[f>>4].wv[:,f] + bv[f]; wave w owns f in [16w,16w+16)
    //           so h(f)==w -> wave reads only ctxv[w][:]
    {
      const int f = wid * 16 + (lane & 15);
      const int i0 = (lane >> 4) * 16;
      float acc = 0.f;
#pragma unroll
      for (int i = 0; i < 16; ++i) acc += ctxv[wid][i0 + i] * wv[(i0 + i) * 64 + f];
      acc += __shfl_xor(acc, 16, 64);
      acc += __shfl_xor(acc, 32, 64);
      if (lane < 16) readf[f] = acc + bv[f];
    }
    __syncthreads();                                          // B9

    // ---- P7b: readv = readf @ wo + bo
    matvec64(wo, bo, readf, readv, wid, lane);
    __syncthreads();                                          // B10

    // ---- P8: hidden = relu(readv @ aw1 + ab1): waves 0,1 full 64-dots
    if (wid < 2) {
      const int k = wid * 64 + lane;
      float acc = 0.f;
#pragma unroll 16
      for (int i = 0; i < 64; ++i) acc += readv[i] * aw1[i * 128 + k];
      hidden[k] = fmaxf(acc + ab1[k], 0.f);
    }
    __syncthreads();                                          // B11

    // ---- P10 (merged): wval = readv @ ww + bw  (independent of P9)
    {
      const int c = wid * 16 + (lane & 15);
      const int i0 = (lane >> 4) * 16;
      float acc = 0.f;
#pragma unroll
      for (int i = 0; i < 16; ++i) acc += readv[i0 + i] * ww[(i0 + i) * 64 + c];
      acc += __shfl_xor(acc, 16, 64);
      acc += __shfl_xor(acc, 32, 64);
      if (lane < 16) wvalv[c] = acc + bw[c];
    }
    // ---- P9: addr_w logits per thread-own column; softmax; result stays in reg
    float aa;
    {
      float acc = ab2[tid];
      const float4* h4 = reinterpret_cast<const float4*>(hidden);
#pragma unroll
      for (int k = 0; k < 32; ++k) {
        float4 hv = h4[k];                  // LDS b128 broadcast
        acc += hv.x * aw2[(4*k+0) * 256 + tid] + hv.y * aw2[(4*k+1) * 256 + tid]
             + hv.z * aw2[(4*k+2) * 256 + tid] + hv.w * aw2[(4*k+3) * 256 + tid];
      }
      float e = __expf(acc);                // logits bounded small -> safe
      float ss = wred_sum(e);
      if (lane == 0) red9[wid] = ss;
      __syncthreads();                                        // B12
      ss = red9[0] + red9[1] + red9[2] + red9[3];
      aa = e / ss;
    }

    // ---- P11: sp(own row) = sp*(1-aa) + wval*aa ; refresh fp16 mirror; no barrier
    //      (next-step B1/B2 order these writes before P2's reads)
    {
      float om = 1.0f - aa;
#pragma unroll
      for (int d = 0; d < D; ++d)
        sp_reg[d] = sp_reg[d] * om + wvalv[d] * aa;
      __half2* rowp = reinterpret_cast<__half2*>(&spm[tid][0]);
#pragma unroll
      for (int p = 0; p < 32; ++p)
        rowp[p] = __float22half2_rn(make_float2(sp_reg[2*p], sp_reg[2*p+1]));
    }
    p0 = fminf(fmaxf(p0 + (1.0f / (float)S), 0.f), 1.f);
  }

  // ---- output: stage 64 fp32 rows at a time through LDS (stride-65: conflict-
  //      free write and read), then fully-coalesced float4 global stores.
  float* stg = reinterpret_cast<float*>(spm);   // 64*65*4 = 16640 B <= 33792 B
  float* ob  = out + (size_t)blockIdx.x * (S * D);
  for (int c = 0; c < 4; ++c) {
    __syncthreads();   // orders prior spm use / prior chunk reads before writes
    if ((tid >> 6) == c) {
      const int r = lane;
#pragma unroll
      for (int d = 0; d < D; ++d) stg[r * 65 + d] = sp_reg[d];
    }
    __syncthreads();
    const int base = c * 64 * D;
#pragma unroll
    for (int i = tid; i < 64 * D / 4; i += TPB) {
      int flat = i << 2, r = flat >> 6, d = flat & 63;
      reinterpret_cast<float4*>(ob + base)[i] =
          make_float4(stg[r*65+d], stg[r*65+d+1], stg[r*65+d+2], stg[r*65+d+3]);
    }
  }
}

extern "C" void kernel_launch(void* const* d_in, const int* in_sizes, int n_in,
                              void* d_out, int out_size, void* d_ws, size_t ws_size,
                              hipStream_t stream) {
  // input order: x(0) register_init(1) scratchpad_init(2) pointer_init(3)
  // wq(4) bq(5) wk(6) bk(7) wv(8) bv(9) wo(10) bo(11) w_write(12) b_write(13)
  // a_w1(14) a_b1(15) a_w2(16) a_b2(17) p_w1(18) p_b1(19) p_w2(20) p_b2(21) num_steps(22)
  // x, register_init, p_w1/p_b1/p_w2/p_b2 are dead for the output (sp).
  const float* sp_init  = (const float*)d_in[2];
  const float* ptr_init = (const float*)d_in[3];
  const float* wq = (const float*)d_in[4];
  const float* bq = (const float*)d_in[5];
  const float* wk = (const float*)d_in[6];
  const float* bk = (const float*)d_in[7];
  const float* wv = (const float*)d_in[8];
  const float* bv = (const float*)d_in[9];
  const float* wo = (const float*)d_in[10];
  const float* bo = (const float*)d_in[11];
  const float* ww = (const float*)d_in[12];
  const float* bw = (const float*)d_in[13];
  const float* aw1 = (const float*)d_in[14];
  const float* ab1 = (const float*)d_in[15];
  const float* aw2 = (const float*)d_in[16];
  const float* ab2 = (const float*)d_in[17];
  const int* nsteps = (const int*)d_in[22];
  float* out = (float*)d_out;
  (void)d_ws; (void)ws_size;

  engine_kernel<<<dim3(NB), dim3(TPB), 0, stream>>>(
      sp_init, ptr_init, wq, bq, wk, bk, wv, bv, wo, bo, ww, bw,
      aw1, ab1, aw2, ab2, nsteps, out);
}

// Round 8
// 1544.068 us; speedup vs baseline: 1.3129x; 1.3129x over previous
//
#include <hip/hip_runtime.h>

// Problem constants (from reference)
#define NB   2048   // batch
#define S    256    // scratchpad slots
#define D    64     // feature dim
#define H    4      // heads
#define HID  128    // MLP hidden
#define TPB  256

__device__ __forceinline__ float wred_sum(float v){
#pragma unroll
  for (int m = 32; m >= 1; m >>= 1) v += __shfl_xor(v, m, 64);
  return v;
}

// y[j] = bias[j] + sum_{i<64} x[i]*W[i*64+j]  -- split-K across lane quadrants,
// wave w owns outputs [16w,16w+16); intra-wave shfl reduce; no cross-wave sync.
__device__ __forceinline__ void matvec64(const float* __restrict__ W,
                                         const float* __restrict__ bias,
                                         const float* x, float* y,
                                         int wid, int lane) {
  const int j  = wid * 16 + (lane & 15);
  const int i0 = (lane >> 4) * 16;
  float acc = 0.f;
#pragma unroll
  for (int i = 0; i < 16; ++i) acc += x[i0 + i] * W[(i0 + i) * 64 + j];
  acc += __shfl_xor(acc, 16, 64);
  acc += __shfl_xor(acc, 32, 64);
  if (lane < 16) y[j] = acc + bias[j];
}

// launch_bounds(256,2): 256-VGPR budget. R5's (256,4) capped VGPR at 64 and
// spilled sp_reg[64] to scratch (FETCH_SIZE 1.78 GB, 2.15x slowdown). The
// register master MUST stay in registers; occupancy 2 blocks/CU is the price.
__global__ __launch_bounds__(TPB, 2)
void engine_kernel(const float* __restrict__ sp_init,
                   const float* __restrict__ ptr_init,
                   const float* __restrict__ wq, const float* __restrict__ bq,
                   const float* __restrict__ wk, const float* __restrict__ bk,
                   const float* __restrict__ wv, const float* __restrict__ bv,
                   const float* __restrict__ wo, const float* __restrict__ bo,
                   const float* __restrict__ ww, const float* __restrict__ bw,
                   const float* __restrict__ aw1, const float* __restrict__ ab1,
                   const float* __restrict__ aw2, const float* __restrict__ ab2,
                   const int*   __restrict__ nsteps,
                   float* __restrict__ out)
{
  // fp32 mirror of sp, pad 65: column access (uniform s, lanes over d) and
  // per-row b32 writes (lane=row) are both conflict-free ((s+d)%32).
  // Master sp state is fp32 in registers (thread owns row tid); the mirror
  // serves the two column-reduction phases and the coalesced epilogue.
  __shared__ float  spm[S][65];                   // 66560 B
  __shared__ __align__(16) float4 attnT[S];       //  4096 B (attn packed by head)
  __shared__ __align__(16) float  addrv[S];       //  1024 B (addr_r)
  __shared__ __align__(16) float4 qkT[D];         //  1024 B (qk packed by head)
  __shared__ __align__(16) float  hidden[HID];    //   512 B
  __shared__ float  ctxv[H][D];                   //  1024 B (atomic target)
  __shared__ float  regv[D];                      //   256 B (atomic target)
  __shared__ float  qhv[D], readf[D], readv[D], wvalv[D]; // 1024 B
  __shared__ float4 red4[4];                      //    64 B
  __shared__ float  red_p1[4], red9[4];           //    32 B
  __shared__ float  qbv[H];                       //    16 B
  // total ~75.6 KB -> 2 blocks/CU (LDS-capped; VGPR free up to 256)

  const int tid  = threadIdx.x;
  const int wid  = tid >> 6;
  const int lane = tid & 63;

  // ---- staging: coalesced global -> LDS, then own row -> registers
  for (int i = tid; i < S * D / 4; i += TPB) {
    float4 v = reinterpret_cast<const float4*>(sp_init)[i];
    int flat = i << 2, s = flat >> 6, d = flat & 63;
    spm[s][d + 0] = v.x; spm[s][d + 1] = v.y; spm[s][d + 2] = v.z; spm[s][d + 3] = v.w;
  }
  if (tid < 64) regv[tid] = 0.f;
  ((float*)ctxv)[tid] = 0.f;
  __syncthreads();

  float sp_reg[D];
#pragma unroll
  for (int d = 0; d < D; ++d) sp_reg[d] = spm[tid][d];   // conflict-free row read

  float p0 = ptr_init[0];
  const int T = *nsteps;
  const float posq = (float)tid * (1.0f / 255.0f);  // linspace(0,1,256)[tid]

  for (int t = 0; t < T; ++t) {
    // ---- P1: addr_r = softmax(-10|pos-p0|). exp in [e^-10,1] -> no max needed.
    {
      float a = __expf(-10.0f * fabsf(posq - p0));
      float ss = wred_sum(a);
      if (lane == 0) red_p1[wid] = ss;
      __syncthreads();                                        // B1
      ss = red_p1[0] + red_p1[1] + red_p1[2] + red_p1[3];
      addrv[tid] = a / ss;
    }
    __syncthreads();                                          // B2

    // ---- P2: regv[d] += sum_{s in wave chunk} addr_r[s]*sp[s][d]
    //      addr chunk preloaded via b128 broadcasts (16 instr vs 64)
    {
      const int d = lane, s0 = wid * 64;
      const float4* ap = reinterpret_cast<const float4*>(&addrv[s0]);
      float acc = 0.f;
#pragma unroll
      for (int j = 0; j < 16; ++j) {
        float4 a4 = ap[j];                  // LDS b128 broadcast
        int s = s0 + (j << 2);
        acc += a4.x * spm[s][d] + a4.y * spm[s + 1][d]
             + a4.z * spm[s + 2][d] + a4.w * spm[s + 3][d];
      }
      atomicAdd(&regv[d], acc);
    }
    __syncthreads();                                          // B3

    // ---- P3: qh = regv @ wq + bq
    matvec64(wq, bq, regv, qhv, wid, lane);
    __syncthreads();                                          // B4

    // ---- P4: qk[h][e] = sum_j wk[e][16h+j]*qh[16h+j]; qb[h] = qh_h . bk_h
    {
      const int h = wid, e = lane;
      float acc = 0.f;
#pragma unroll
      for (int j = 0; j < 16; ++j) acc += wk[e * 64 + h * 16 + j] * qhv[h * 16 + j];
      ((float*)qkT)[e * 4 + h] = acc;
      if (tid < 4) {
        float qb = 0.f;
#pragma unroll
        for (int j = 0; j < 16; ++j) qb += qhv[tid * 16 + j] * bk[tid * 16 + j];
        qbv[tid] = qb;
      }
      if (tid < 64) regv[tid] = 0.f;   // re-arm P2 accumulator (dead until next step)
    }
    __syncthreads();                                          // B5

    // ---- P5: scores from REGISTER sp + qkT broadcast; per-head softmax (no max:
    //          logits bounded to a few units -> fp32 exp safe; validated R5
    //          absmax 4.7e-10)
    {
      float s0 = qbv[0], s1 = qbv[1], s2 = qbv[2], s3 = qbv[3];
#pragma unroll 16
      for (int e = 0; e < 64; ++e) {
        float4 qk = qkT[e];                 // LDS b128 broadcast
        float v = sp_reg[e];
        s0 += v * qk.x; s1 += v * qk.y; s2 += v * qk.z; s3 += v * qk.w;
      }
      float e0 = __expf(s0 * 0.25f), e1 = __expf(s1 * 0.25f);
      float e2 = __expf(s2 * 0.25f), e3 = __expf(s3 * 0.25f);
      float r0 = e0, r1 = e1, r2 = e2, r3 = e3;
#pragma unroll
      for (int m = 32; m >= 1; m >>= 1) {
        r0 += __shfl_xor(r0, m, 64); r1 += __shfl_xor(r1, m, 64);
        r2 += __shfl_xor(r2, m, 64); r3 += __shfl_xor(r3, m, 64);
      }
      if (lane == 0) red4[wid] = make_float4(r0, r1, r2, r3);
      __syncthreads();                                        // B6
      float4 t0 = red4[0], t1 = red4[1], t2 = red4[2], t3 = red4[3];
      float i0 = 1.0f / (t0.x + t1.x + t2.x + t3.x);
      float i1 = 1.0f / (t0.y + t1.y + t2.y + t3.y);
      float i2 = 1.0f / (t0.z + t1.z + t2.z + t3.z);
      float i3 = 1.0f / (t0.w + t1.w + t2.w + t3.w);
      attnT[tid] = make_float4(e0 * i0, e1 * i1, e2 * i2, e3 * i3);
      ((float*)ctxv)[tid] = 0.f;          // re-arm P6 accumulator (dead since P7a(t-1))
    }
    __syncthreads();                                          // B7

    // ---- P6: ctx[h][d] += sum_{s in chunk} attn[h][s]*sp[s][d]
    {
      const int d = lane, s0 = wid * 64;
      float c0 = 0, c1 = 0, c2 = 0, c3 = 0;
#pragma unroll 8
      for (int i = 0; i < 64; ++i) {
        int s = s0 + i;
        float sv = spm[s][d];
        float4 at = attnT[s];               // LDS b128 broadcast
        c0 += at.x * sv; c1 += at.y * sv; c2 += at.z * sv; c3 += at.w * sv;
      }
      atomicAdd(&ctxv[0][d], c0); atomicAdd(&ctxv[1][d], c1);
      atomicAdd(&ctxv[2][d], c2); atomicAdd(&ctxv[3][d], c3);
    }
    __syncthreads();                                          // B8

    // ---- P7a: readf[f] = ctx[f>>4].wv[:,f] + bv[f]; wave w owns f in [16w,16w+16)
    //           so h(f)==w -> wave reads only ctxv[w][:]
    {
      const int f = wid * 16 + (lane & 15);
      const int i0 = (lane >> 4) * 16;
      float acc = 0.f;
#pragma unroll
      for (int i = 0; i < 16; ++i) acc += ctxv[wid][i0 + i] * wv[(i0 + i) * 64 + f];
      acc += __shfl_xor(acc, 16, 64);
      acc += __shfl_xor(acc, 32, 64);
      if (lane < 16) readf[f] = acc + bv[f];
    }
    __syncthreads();                                          // B9

    // ---- P7b: readv = readf @ wo + bo
    matvec64(wo, bo, readf, readv, wid, lane);
    __syncthreads();                                          // B10

    // ---- P8: hidden = relu(readv @ aw1 + ab1): waves 0,1 full 64-dots
    if (wid < 2) {
      const int k = wid * 64 + lane;
      float acc = 0.f;
#pragma unroll 16
      for (int i = 0; i < 64; ++i) acc += readv[i] * aw1[i * 128 + k];
      hidden[k] = fmaxf(acc + ab1[k], 0.f);
    }
    __syncthreads();                                          // B11

    // ---- P10 (merged): wval = readv @ ww + bw  (independent of P9)
    {
      const int c = wid * 16 + (lane & 15);
      const int i0 = (lane >> 4) * 16;
      float acc = 0.f;
#pragma unroll
      for (int i = 0; i < 16; ++i) acc += readv[i0 + i] * ww[(i0 + i) * 64 + c];
      acc += __shfl_xor(acc, 16, 64);
      acc += __shfl_xor(acc, 32, 64);
      if (lane < 16) wvalv[c] = acc + bw[c];
    }
    // ---- P9: addr_w logits per thread-own column; softmax; result stays in reg
    float aa;
    {
      float acc = ab2[tid];
      const float4* h4 = reinterpret_cast<const float4*>(hidden);
#pragma unroll 8
      for (int k = 0; k < 32; ++k) {
        float4 hv = h4[k];                  // LDS b128 broadcast
        acc += hv.x * aw2[(4*k+0) * 256 + tid] + hv.y * aw2[(4*k+1) * 256 + tid]
             + hv.z * aw2[(4*k+2) * 256 + tid] + hv.w * aw2[(4*k+3) * 256 + tid];
      }
      float e = __expf(acc);                // logits bounded small -> safe
      float ss = wred_sum(e);
      if (lane == 0) red9[wid] = ss;
      __syncthreads();                                        // B12
      ss = red9[0] + red9[1] + red9[2] + red9[3];
      aa = e / ss;
    }

    // ---- P11: sp(own row) = sp*(1-aa) + wval*aa ; refresh fp32 mirror (b32
    //      row writes, conflict-free via pad-65). Next-step B1/B2 order these
    //      writes before P2's reads.
    {
      float om = 1.0f - aa;
#pragma unroll
      for (int d = 0; d < D; ++d) {
        sp_reg[d] = sp_reg[d] * om + wvalv[d] * aa;
        spm[tid][d] = sp_reg[d];
      }
    }
    p0 = fminf(fmaxf(p0 + (1.0f / (float)S), 0.f), 1.f);
  }

  // ---- output: the mirror already holds the final fp32 sp -> coalesced copy-out
  __syncthreads();
  float* ob = out + (size_t)blockIdx.x * (S * D);
  for (int i = tid; i < S * D / 4; i += TPB) {
    int flat = i << 2, s = flat >> 6, d = flat & 63;
    reinterpret_cast<float4*>(ob)[i] =
        make_float4(spm[s][d], spm[s][d + 1], spm[s][d + 2], spm[s][d + 3]);
  }
}

extern "C" void kernel_launch(void* const* d_in, const int* in_sizes, int n_in,
                              void* d_out, int out_size, void* d_ws, size_t ws_size,
                              hipStream_t stream) {
  // input order: x(0) register_init(1) scratchpad_init(2) pointer_init(3)
  // wq(4) bq(5) wk(6) bk(7) wv(8) bv(9) wo(10) bo(11) w_write(12) b_write(13)
  // a_w1(14) a_b1(15) a_w2(16) a_b2(17) p_w1(18) p_b1(19) p_w2(20) p_b2(21) num_steps(22)
  // x, register_init, p_w1/p_b1/p_w2/p_b2 are dead for the output (sp).
  const float* sp_init  = (const float*)d_in[2];
  const float* ptr_init = (const float*)d_in[3];
  const float* wq = (const float*)d_in[4];
  const float* bq = (const float*)d_in[5];
  const float* wk = (const float*)d_in[6];
  const float* bk = (const float*)d_in[7];
  const float* wv = (const float*)d_in[8];
  const float* bv = (const float*)d_in[9];
  const float* wo = (const float*)d_in[10];
  const float* bo = (const float*)d_in[11];
  const float* ww = (const float*)d_in[12];
  const float* bw = (const float*)d_in[13];
  const float* aw1 = (const float*)d_in[14];
  const float* ab1 = (const float*)d_in[15];
  const float* aw2 = (const float*)d_in[16];
  const float* ab2 = (const float*)d_in[17];
  const int* nsteps = (const int*)d_in[22];
  float* out = (float*)d_out;
  (void)d_ws; (void)ws_size;

  engine_kernel<<<dim3(NB), dim3(TPB), 0, stream>>>(
      sp_init, ptr_init, wq, bq, wk, bk, wv, bv, wo, bo, ww, bw,
      aw1, ab1, aw2, ab2, nsteps, out);
}

// Round 9
// 902.209 us; speedup vs baseline: 2.2469x; 1.7114x over previous
//
#include <hip/hip_runtime.h>

// Problem constants (from reference)
#define NB   2048   // batch
#define S    256    // scratchpad slots
#define D    64     // feature dim
#define H    4      // heads
#define HID  128    // MLP hidden
#define TPB  256

__device__ __forceinline__ float wred_sum(float v){
#pragma unroll
  for (int m = 32; m >= 1; m >>= 1) v += __shfl_xor(v, m, 64);
  return v;
}

// y[j] = bias[j] + sum_{i<64} x[i]*W[i*64+j]  -- split-K across lane quadrants,
// wave w owns outputs [16w,16w+16); intra-wave shfl reduce; no cross-wave sync.
__device__ __forceinline__ void matvec64(const float* __restrict__ W,
                                         const float* __restrict__ bias,
                                         const float* x, float* y,
                                         int wid, int lane) {
  const int j  = wid * 16 + (lane & 15);
  const int i0 = (lane >> 4) * 16;
  float acc = 0.f;
#pragma unroll
  for (int i = 0; i < 16; ++i) acc += x[i0 + i] * W[(i0 + i) * 64 + j];
  acc += __shfl_xor(acc, 16, 64);
  acc += __shfl_xor(acc, 32, 64);
  if (lane < 16) y[j] = acc + bias[j];
}

// launch_bounds(256,2): 256-VGPR budget (2 waves/EU). R5's (256,4) capped VGPR
// at 64 and spilled. R8's spill had a DIFFERENT cause: P5 used `#pragma unroll
// 16` (partial) -> runtime-indexed sp_reg[e] -> localMem (rule #20), shown by
// WRITE_SIZE 1.3 GB == spill-write arithmetic. Fix: FULL unroll wherever
// sp_reg is indexed.
__global__ __launch_bounds__(TPB, 2)
void engine_kernel(const float* __restrict__ sp_init,
                   const float* __restrict__ ptr_init,
                   const float* __restrict__ wq, const float* __restrict__ bq,
                   const float* __restrict__ wk, const float* __restrict__ bk,
                   const float* __restrict__ wv, const float* __restrict__ bv,
                   const float* __restrict__ wo, const float* __restrict__ bo,
                   const float* __restrict__ ww, const float* __restrict__ bw,
                   const float* __restrict__ aw1, const float* __restrict__ ab1,
                   const float* __restrict__ aw2, const float* __restrict__ ab2,
                   const int*   __restrict__ nsteps,
                   float* __restrict__ out)
{
  // fp32 mirror of sp, pad 65: column access (uniform s, lanes over d) and
  // per-row b32 writes (lane=row) are both conflict-free ((s+d)%32).
  // Master sp state is fp32 in registers (thread owns row tid); the mirror
  // serves the two column-reduction phases and the coalesced epilogue.
  __shared__ float  spm[S][65];                   // 66560 B
  __shared__ __align__(16) float4 attnT[S];       //  4096 B (attn packed by head)
  __shared__ __align__(16) float  addrv[S];       //  1024 B (addr_r)
  __shared__ __align__(16) float4 qkT[D];         //  1024 B (qk packed by head)
  __shared__ __align__(16) float  hidden[HID];    //   512 B
  __shared__ float  ctxv[H][D];                   //  1024 B (atomic target)
  __shared__ float  regv[D];                      //   256 B (atomic target)
  __shared__ float  qhv[D], readf[D], readv[D], wvalv[D]; // 1024 B
  __shared__ float4 red4[4];                      //    64 B
  __shared__ float  red_p1[4], red9[4];           //    32 B
  __shared__ float  qbv[H];                       //    16 B
  // total ~75.6 KB -> 2 blocks/CU (LDS-capped; VGPR free up to 256)

  const int tid  = threadIdx.x;
  const int wid  = tid >> 6;
  const int lane = tid & 63;

  // ---- staging: coalesced global -> LDS, then own row -> registers
  for (int i = tid; i < S * D / 4; i += TPB) {
    float4 v = reinterpret_cast<const float4*>(sp_init)[i];
    int flat = i << 2, s = flat >> 6, d = flat & 63;
    spm[s][d + 0] = v.x; spm[s][d + 1] = v.y; spm[s][d + 2] = v.z; spm[s][d + 3] = v.w;
  }
  if (tid < 64) regv[tid] = 0.f;
  ((float*)ctxv)[tid] = 0.f;
  __syncthreads();

  float sp_reg[D];
#pragma unroll
  for (int d = 0; d < D; ++d) sp_reg[d] = spm[tid][d];   // conflict-free row read

  float p0 = ptr_init[0];
  const int T = *nsteps;
  const float posq = (float)tid * (1.0f / 255.0f);  // linspace(0,1,256)[tid]

  for (int t = 0; t < T; ++t) {
    // ---- P1: addr_r = softmax(-10|pos-p0|). exp in [e^-10,1] -> no max needed.
    {
      float a = __expf(-10.0f * fabsf(posq - p0));
      float ss = wred_sum(a);
      if (lane == 0) red_p1[wid] = ss;
      __syncthreads();                                        // B1
      ss = red_p1[0] + red_p1[1] + red_p1[2] + red_p1[3];
      addrv[tid] = a / ss;
    }
    __syncthreads();                                          // B2

    // ---- P2: regv[d] += sum_{s in wave chunk} addr_r[s]*sp[s][d]
    //      addr chunk preloaded via b128 broadcasts (16 instr vs 64)
    {
      const int d = lane, s0 = wid * 64;
      const float4* ap = reinterpret_cast<const float4*>(&addrv[s0]);
      float acc = 0.f;
#pragma unroll
      for (int j = 0; j < 16; ++j) {
        float4 a4 = ap[j];                  // LDS b128 broadcast
        int s = s0 + (j << 2);
        acc += a4.x * spm[s][d] + a4.y * spm[s + 1][d]
             + a4.z * spm[s + 2][d] + a4.w * spm[s + 3][d];
      }
      atomicAdd(&regv[d], acc);
    }
    __syncthreads();                                          // B3

    // ---- P3: qh = regv @ wq + bq
    matvec64(wq, bq, regv, qhv, wid, lane);
    __syncthreads();                                          // B4

    // ---- P4: qk[h][e] = sum_j wk[e][16h+j]*qh[16h+j]; qb[h] = qh_h . bk_h
    {
      const int h = wid, e = lane;
      float acc = 0.f;
#pragma unroll
      for (int j = 0; j < 16; ++j) acc += wk[e * 64 + h * 16 + j] * qhv[h * 16 + j];
      ((float*)qkT)[e * 4 + h] = acc;
      if (tid < 4) {
        float qb = 0.f;
#pragma unroll
        for (int j = 0; j < 16; ++j) qb += qhv[tid * 16 + j] * bk[tid * 16 + j];
        qbv[tid] = qb;
      }
      if (tid < 64) regv[tid] = 0.f;   // re-arm P2 accumulator (dead until next step)
    }
    __syncthreads();                                          // B5

    // ---- P5: scores from REGISTER sp + qkT broadcast; per-head softmax.
    //      FULL unroll is mandatory: partial unroll makes sp_reg[e] runtime-
    //      indexed -> localMem spill (R8: WRITE_SIZE 1.3 GB, +62% dur).
    {
      float s0 = qbv[0], s1 = qbv[1], s2 = qbv[2], s3 = qbv[3];
#pragma unroll
      for (int e = 0; e < 64; ++e) {
        float4 qk = qkT[e];                 // LDS b128 broadcast
        float v = sp_reg[e];
        s0 += v * qk.x; s1 += v * qk.y; s2 += v * qk.z; s3 += v * qk.w;
      }
      float e0 = __expf(s0 * 0.25f), e1 = __expf(s1 * 0.25f);
      float e2 = __expf(s2 * 0.25f), e3 = __expf(s3 * 0.25f);
      float r0 = e0, r1 = e1, r2 = e2, r3 = e3;
#pragma unroll
      for (int m = 32; m >= 1; m >>= 1) {
        r0 += __shfl_xor(r0, m, 64); r1 += __shfl_xor(r1, m, 64);
        r2 += __shfl_xor(r2, m, 64); r3 += __shfl_xor(r3, m, 64);
      }
      if (lane == 0) red4[wid] = make_float4(r0, r1, r2, r3);
      __syncthreads();                                        // B6
      float4 t0 = red4[0], t1 = red4[1], t2 = red4[2], t3 = red4[3];
      float i0 = 1.0f / (t0.x + t1.x + t2.x + t3.x);
      float i1 = 1.0f / (t0.y + t1.y + t2.y + t3.y);
      float i2 = 1.0f / (t0.z + t1.z + t2.z + t3.z);
      float i3 = 1.0f / (t0.w + t1.w + t2.w + t3.w);
      attnT[tid] = make_float4(e0 * i0, e1 * i1, e2 * i2, e3 * i3);
      ((float*)ctxv)[tid] = 0.f;          // re-arm P6 accumulator (dead since P7a(t-1))
    }
    __syncthreads();                                          // B7

    // ---- P6: ctx[h][d] += sum_{s in chunk} attn[h][s]*sp[s][d]
    {
      const int d = lane, s0 = wid * 64;
      float c0 = 0, c1 = 0, c2 = 0, c3 = 0;
#pragma unroll 8
      for (int i = 0; i < 64; ++i) {
        int s = s0 + i;
        float sv = spm[s][d];
        float4 at = attnT[s];               // LDS b128 broadcast
        c0 += at.x * sv; c1 += at.y * sv; c2 += at.z * sv; c3 += at.w * sv;
      }
      atomicAdd(&ctxv[0][d], c0); atomicAdd(&ctxv[1][d], c1);
      atomicAdd(&ctxv[2][d], c2); atomicAdd(&ctxv[3][d], c3);
    }
    __syncthreads();                                          // B8

    // ---- P7a: readf[f] = ctx[f>>4].wv[:,f] + bv[f]; wave w owns f in [16w,16w+16)
    //           so h(f)==w -> wave reads only ctxv[w][:]
    {
      const int f = wid * 16 + (lane & 15);
      const int i0 = (lane >> 4) * 16;
      float acc = 0.f;
#pragma unroll
      for (int i = 0; i < 16; ++i) acc += ctxv[wid][i0 + i] * wv[(i0 + i) * 64 + f];
      acc += __shfl_xor(acc, 16, 64);
      acc += __shfl_xor(acc, 32, 64);
      if (lane < 16) readf[f] = acc + bv[f];
    }
    __syncthreads();                                          // B9

    // ---- P7b: readv = readf @ wo + bo
    matvec64(wo, bo, readf, readv, wid, lane);
    __syncthreads();                                          // B10

    // ---- P8: hidden = relu(readv @ aw1 + ab1): waves 0,1 full 64-dots
    if (wid < 2) {
      const int k = wid * 64 + lane;
      float acc = 0.f;
#pragma unroll 16
      for (int i = 0; i < 64; ++i) acc += readv[i] * aw1[i * 128 + k];
      hidden[k] = fmaxf(acc + ab1[k], 0.f);
    }
    __syncthreads();                                          // B11

    // ---- P10 (merged): wval = readv @ ww + bw  (independent of P9)
    {
      const int c = wid * 16 + (lane & 15);
      const int i0 = (lane >> 4) * 16;
      float acc = 0.f;
#pragma unroll
      for (int i = 0; i < 16; ++i) acc += readv[i0 + i] * ww[(i0 + i) * 64 + c];
      acc += __shfl_xor(acc, 16, 64);
      acc += __shfl_xor(acc, 32, 64);
      if (lane < 16) wvalv[c] = acc + bw[c];
    }
    // ---- P9: addr_w logits per thread-own column; softmax; result stays in reg
    float aa;
    {
      float acc = ab2[tid];
      const float4* h4 = reinterpret_cast<const float4*>(hidden);
#pragma unroll 8
      for (int k = 0; k < 32; ++k) {
        float4 hv = h4[k];                  // LDS b128 broadcast
        acc += hv.x * aw2[(4*k+0) * 256 + tid] + hv.y * aw2[(4*k+1) * 256 + tid]
             + hv.z * aw2[(4*k+2) * 256 + tid] + hv.w * aw2[(4*k+3) * 256 + tid];
      }
      float e = __expf(acc);                // logits bounded small -> safe
      float ss = wred_sum(e);
      if (lane == 0) red9[wid] = ss;
      __syncthreads();                                        // B12
      ss = red9[0] + red9[1] + red9[2] + red9[3];
      aa = e / ss;
    }

    // ---- P11: sp(own row) = sp*(1-aa) + wval*aa ; refresh fp32 mirror (b32
    //      row writes, conflict-free via pad-65). Next-step B1/B2 order these
    //      writes before P2's reads. FULL unroll (static sp_reg indexing).
    {
      float om = 1.0f - aa;
#pragma unroll
      for (int d = 0; d < D; ++d) {
        sp_reg[d] = sp_reg[d] * om + wvalv[d] * aa;
        spm[tid][d] = sp_reg[d];
      }
    }
    p0 = fminf(fmaxf(p0 + (1.0f / (float)S), 0.f), 1.f);
  }

  // ---- output: the mirror already holds the final fp32 sp -> coalesced copy-out
  __syncthreads();
  float* ob = out + (size_t)blockIdx.x * (S * D);
  for (int i = tid; i < S * D / 4; i += TPB) {
    int flat = i << 2, s = flat >> 6, d = flat & 63;
    reinterpret_cast<float4*>(ob)[i] =
        make_float4(spm[s][d], spm[s][d + 1], spm[s][d + 2], spm[s][d + 3]);
  }
}

extern "C" void kernel_launch(void* const* d_in, const int* in_sizes, int n_in,
                              void* d_out, int out_size, void* d_ws, size_t ws_size,
                              hipStream_t stream) {
  // input order: x(0) register_init(1) scratchpad_init(2) pointer_init(3)
  // wq(4) bq(5) wk(6) bk(7) wv(8) bv(9) wo(10) bo(11) w_write(12) b_write(13)
  // a_w1(14) a_b1(15) a_w2(16) a_b2(17) p_w1(18) p_b1(19) p_w2(20) p_b2(21) num_steps(22)
  // x, register_init, p_w1/p_b1/p_w2/p_b2 are dead for the output (sp).
  const float* sp_init  = (const float*)d_in[2];
  const float* ptr_init = (const float*)d_in[3];
  const float* wq = (const float*)d_in[4];
  const float* bq = (const float*)d_in[5];
  const float* wk = (const float*)d_in[6];
  const float* bk = (const float*)d_in[7];
  const float* wv = (const float*)d_in[8];
  const float* bv = (const float*)d_in[9];
  const float* wo = (const float*)d_in[10];
  const float* bo = (const float*)d_in[11];
  const float* ww = (const float*)d_in[12];
  const float* bw = (const float*)d_in[13];
  const float* aw1 = (const float*)d_in[14];
  const float* ab1 = (const float*)d_in[15];
  const float* aw2 = (const float*)d_in[16];
  const float* ab2 = (const float*)d_in[17];
  const int* nsteps = (const int*)d_in[22];
  float* out = (float*)d_out;
  (void)d_ws; (void)ws_size;

  engine_kernel<<<dim3(NB), dim3(TPB), 0, stream>>>(
      sp_init, ptr_init, wq, bq, wk, bk, wv, bv, wo, bo, ww, bw,
      aw1, ab1, aw2, ab2, nsteps, out);
}